// Round 2
// baseline (337.306 us; speedup 1.0000x reference)
//
#include <hip/hip_runtime.h>

#define IMG 512
#define OUT_R 16
#define OUT_C 128
#define HALO 5
#define IN_R 26          // OUT_R + 2*HALO
#define IN_C 138         // OUT_C + 2*HALO
#define CPAD 144         // padded col count = 9 MFMA col-tiles of 16
#define VS 152           // vbuf row stride in halfs (304B, bank-staggered)
#define NT 256
#define NSLOTS 64

typedef _Float16 f16x8 __attribute__((ext_vector_type(8)));
typedef float    f32x4 __attribute__((ext_vector_type(4)));

static constexpr float GWf[11] = {
    0.00102838f, 0.00759876f, 0.03600077f, 0.10936053f, 0.21300556f,
    0.26601170f, 0.21300556f, 0.10936053f, 0.03600077f, 0.00759876f,
    0.00102838f };

// Per-lane constant MFMA fragment of the banded weight matrix W[k][j] = w[k-j].
// Identical values serve as A-frag (vertical: Wv[i][k] = w[k-i]) and B-frag
// (horizontal: Wh[k][j] = w[k-j]) because the A and B fragment (lane,elem)->k
// maps are the same function -> any k-permutation cancels between A and B.
struct WTab { alignas(16) _Float16 v[4][16][8]; };
static constexpr WTab make_wtab() {
    WTab t{};
    for (int g = 0; g < 4; ++g)
        for (int j = 0; j < 16; ++j)
            for (int b = 0; b < 8; ++b) {
                const int d = 8 * g + b - j;
                t.v[g][j][b] = (d >= 0 && d <= 10) ? (_Float16)GWf[d]
                                                   : (_Float16)0.f;
            }
    return t;
}
__device__ constexpr WTab WTAB = make_wtab();

// chbuf: column-major [ch][col][32 rows]; 16B slot g holds rows 8g..8g+7,
// stored at physical slot (g ^ ((col>>1)&3)) -> conflict-free b128 r/w.
// vbuf: row-major [ch][row][VS], aliased over chbuf after vertical reads.
union SMem {
    _Float16 ch[4][CPAD][32];     // 36864 B  (full union extent)
    _Float16 vb[4][OUT_R][VS];    // 19456 B
};
static_assert(sizeof(SMem) == 4 * CPAD * 32 * 2, "smem size");

// One column-half task: column c (0..143), rows rh*16 .. rh*16+15.
// 288 tasks cover EVERY byte of chbuf -> no uninitialized LDS anywhere.
__device__ __forceinline__ void prep_task(int task, int c0, int y0,
                                          size_t pbase,
                                          const float* __restrict__ den,
                                          const float* __restrict__ cln,
                                          SMem* sm) {
    const int rh = (task >= CPAD) ? 1 : 0;
    const int c  = task - CPAD * rh;
    const int gc = c0 - HALO + c;
    const bool colok = ((unsigned)gc < IMG) && (c < IN_C);
    union { f16x8 v8[8]; _Float16 h[64]; } st;
    const int r0 = rh * 16;
#pragma unroll
    for (int rr = 0; rr < 16; ++rr) {
        const int R  = r0 + rr;
        const int gr = y0 - HALO + R;
        float x = 0.f, y = 0.f;
        if (colok && ((unsigned)gr < IMG) && (R < IN_R)) {
            const size_t idx = pbase + (size_t)gr * IMG + gc;
            x = den[idx]; y = cln[idx];
        }
        x = fminf(fmaxf(x, 0.f), 1.f);   // v_med3_f32
        y = fminf(fmaxf(y, 0.f), 1.f);
        st.h[rr]      = (_Float16)x;
        st.h[16 + rr] = (_Float16)y;
        st.h[32 + rr] = (_Float16)fmaf(x, x, y * y);
        st.h[48 + rr] = (_Float16)(x * y);
    }
    const int sw = (c >> 1) & 3;
#pragma unroll
    for (int ch = 0; ch < 4; ++ch) {
#pragma unroll
        for (int gg = 0; gg < 2; ++gg) {
            const int g = rh * 2 + gg;
            *reinterpret_cast<f16x8*>(&sm->ch[ch][c][(g ^ sw) * 8]) =
                st.v8[ch * 2 + gg];
        }
    }
}

__global__ __launch_bounds__(NT, 4)
void ssim_mfma(const float* __restrict__ den, const float* __restrict__ cln,
               double* __restrict__ slots) {
    __shared__ SMem sm;
    __shared__ float red[NT / 64];

    const int t    = threadIdx.x;
    const int lane = t & 63;
    const int w    = t >> 6;
    const int fj   = lane & 15;   // MFMA i/j index
    const int fg   = lane >> 4;   // MFMA k-group

    // XCD-chunked swizzle: consecutive vids (sharing halo rows) on one XCD
    const int bid = blockIdx.x;
    int vid = bid;
    if ((gridDim.x & 7) == 0) {
        const int chunk = gridDim.x >> 3;
        vid = (bid & 7) * chunk + (bid >> 3);
    }
    const int rs    = vid & 31;
    const int cs    = (vid >> 5) & 3;
    const int plane = vid >> 7;
    const int c0 = cs * OUT_C;
    const int y0 = rs * OUT_R;
    const size_t pbase = (size_t)plane * (IMG * IMG);

    const f16x8 wf = *reinterpret_cast<const f16x8*>(WTAB.v[fg][fj]);

    // ---------------- Phase 1: prep 4 channels in f16 into LDS -------------
    prep_task(t, c0, y0, pbase, den, cln, &sm);
    if (t < 2 * CPAD - NT)                          // 32 leftover tasks
        prep_task(NT + t, c0, y0, pbase, den, cln, &sm);
    __syncthreads();

    // ---------------- Phase 2: vertical conv via MFMA ----------------------
    // D = Wv(16x32) * chbuf(32 x 16cols); 9 tiles * 4 ch = 36 tasks, 9/wave
    const f32x4 zero4 = {0.f, 0.f, 0.f, 0.f};
    f32x4 acc[9];
#pragma unroll
    for (int n = 0; n < 9; ++n) {
        const int tau  = 9 * w + n;
        const int tile = tau >> 2;
        const int ch   = tau & 3;
        const int colp = tile * 16 + fj;
        const f16x8 bf = *reinterpret_cast<const f16x8*>(
            &sm.ch[ch][colp][(fg ^ ((colp >> 1) & 3)) * 8]);
        acc[n] = __builtin_amdgcn_mfma_f32_16x16x32_f16(wf, bf, zero4, 0, 0, 0);
    }
    __syncthreads();   // all chbuf reads done -> safe to alias vb over it
#pragma unroll
    for (int n = 0; n < 9; ++n) {
        const int tau  = 9 * w + n;
        const int tile = tau >> 2;
        const int ch   = tau & 3;
#pragma unroll
        for (int b = 0; b < 4; ++b)
            sm.vb[ch][4 * fg + b][tile * 16 + fj] = (_Float16)acc[n][b];
    }
    __syncthreads();

    // ---------------- Phase 3: horizontal conv via MFMA + SSIM -------------
    // D = vbuf(16rows x K=32cols) * Wh(32x16); 8 out-tiles, 2 per wave
    float sacc = 0.f;
#pragma unroll
    for (int mt = 0; mt < 2; ++mt) {
        const int m = 2 * w + mt;
        f32x4 d[4];
#pragma unroll
        for (int ch = 0; ch < 4; ++ch) {
            const f16x8 af = *reinterpret_cast<const f16x8*>(
                &sm.vb[ch][fj][m * 16 + 8 * fg]);
            d[ch] = __builtin_amdgcn_mfma_f32_16x16x32_f16(af, wf, zero4, 0, 0, 0);
        }
#pragma unroll
        for (int b = 0; b < 4; ++b) {
            const float C1 = 1e-4f, C2 = 9e-4f;
            const float mu1 = d[0][b], mu2 = d[1][b];
            const float qb  = d[2][b], pb  = d[3][b];
            const float mu1s = mu1 * mu1, mu2s = mu2 * mu2, mu12 = mu1 * mu2;
            const float ssum = qb - mu1s - mu2s;    // sigma1_sq + sigma2_sq
            const float s12  = pb - mu12;
            const float num  = fmaf(2.f, mu12, C1) * fmaf(2.f, s12, C2);
            const float dnm  = (mu1s + mu2s + C1) * (ssum + C2);
            sacc = fmaf(num, __builtin_amdgcn_rcpf(dnm), sacc);
        }
    }

    // ---------------- block reduction, one f64 atomic per block ------------
#pragma unroll
    for (int off = 32; off > 0; off >>= 1)
        sacc += __shfl_down(sacc, off, 64);
    if (lane == 0) red[w] = sacc;
    __syncthreads();
    if (t == 0) {
        const float s = red[0] + red[1] + red[2] + red[3];
        atomicAdd(&slots[(size_t)(bid & (NSLOTS - 1)) * 8], (double)s);
    }
}

__global__ void ssim_finalize(const double* __restrict__ slots,
                              float* __restrict__ out, double inv_n) {
    double s = 0.0;
    for (int i = 0; i < NSLOTS; ++i) s += slots[i * 8];
    out[0] = 1.0f - (float)(s * inv_n);
}

extern "C" void kernel_launch(void* const* d_in, const int* in_sizes, int n_in,
                              void* d_out, int out_size, void* d_ws,
                              size_t ws_size, hipStream_t stream) {
    const float* den = (const float*)d_in[0];
    const float* cln = (const float*)d_in[1];
    float* out = (float*)d_out;
    double* slots = (double*)d_ws;

    hipMemsetAsync(d_ws, 0, NSLOTS * 64, stream);

    const int n = in_sizes[0];                  // 32*3*512*512 elements
    const int planes = n / (IMG * IMG);         // 96
    dim3 grid(planes * (IMG / OUT_R) * (IMG / OUT_C));   // 96*32*4 = 12288
    ssim_mfma<<<grid, NT, 0, stream>>>(den, cln, slots);
    ssim_finalize<<<1, 1, 0, stream>>>(slots, out, 1.0 / (double)n);
}

// Round 3
// 273.936 us; speedup vs baseline: 1.2313x; 1.2313x over previous
//
#include <hip/hip_runtime.h>

#define IMG 512
#define OUT_R 16
#define OUT_C 64
#define HALO 5
#define IN_R 26          // OUT_R + 2*HALO
#define IN_C 74          // OUT_C + 2*HALO
#define CPAD 80          // padded col count = 5 MFMA col-tiles of 16
#define NVTILE 5         // vertical col-tiles
#define VS 88            // vbuf row stride in halfs (176B, bank-staggered)
#define NT 256
#define NSLOTS 64

typedef _Float16 f16x8 __attribute__((ext_vector_type(8)));
typedef float    f32x4 __attribute__((ext_vector_type(4)));

static constexpr float GWf[11] = {
    0.00102838f, 0.00759876f, 0.03600077f, 0.10936053f, 0.21300556f,
    0.26601170f, 0.21300556f, 0.10936053f, 0.03600077f, 0.00759876f,
    0.00102838f };

// Per-lane constant MFMA fragment of the banded weight matrix W[k][j] = w[k-j].
// Identical values serve as A-frag (vertical: Wv[i][k] = w[k-i]) and B-frag
// (horizontal: Wh[k][j] = w[k-j]) because the A and B fragment (lane,elem)->k
// maps are the same function -> any k-permutation cancels between A and B.
// (Correctness of this + the D layout proven by R2's absmax=0 pass.)
struct WTab { alignas(16) _Float16 v[4][16][8]; };
static constexpr WTab make_wtab() {
    WTab t{};
    for (int g = 0; g < 4; ++g)
        for (int j = 0; j < 16; ++j)
            for (int b = 0; b < 8; ++b) {
                const int d = 8 * g + b - j;
                t.v[g][j][b] = (d >= 0 && d <= 10) ? (_Float16)GWf[d]
                                                   : (_Float16)0.f;
            }
    return t;
}
__device__ constexpr WTab WTAB = make_wtab();

// chbuf: column-major [ch][col][32 rows]; 16B slot g holds rows 8g..8g+7,
// stored at physical slot (g ^ ((col>>1)&3)) -> conflict-free b128 r/w.
// vbuf+red alias over chbuf after vertical reads complete (barrier-guarded).
// sizeof == 20480 B exactly == 160 KiB / 8 -> 8 blocks/CU residency.
union SMem {
    _Float16 ch[4][CPAD][32];                       // 20480 B
    struct { _Float16 vb[4][OUT_R][VS]; float red[8]; } s;   // 11296 B
};
static_assert(sizeof(SMem) == 4 * CPAD * 32 * 2, "smem size");

// One task: column c (0..79), row-group g (0..3) = rows 8g..8g+7.
// 320 tasks cover EVERY byte of chbuf -> no uninitialized LDS anywhere.
__device__ __forceinline__ void prep_task(int task, int c0, int y0,
                                          size_t pbase,
                                          const float* __restrict__ den,
                                          const float* __restrict__ cln,
                                          SMem* sm) {
    const int c = task % CPAD;
    const int g = task / CPAD;
    const int gc = c0 - HALO + c;
    const bool colok = ((unsigned)gc < IMG) && (c < IN_C);
    union { f16x8 v8[4]; _Float16 h[32]; } st;
    const int r0 = g * 8;
#pragma unroll
    for (int rr = 0; rr < 8; ++rr) {
        const int R  = r0 + rr;
        const int gr = y0 - HALO + R;
        float x = 0.f, y = 0.f;
        if (colok && ((unsigned)gr < IMG) && (R < IN_R)) {
            const size_t idx = pbase + (size_t)gr * IMG + gc;
            x = den[idx]; y = cln[idx];
        }
        x = fminf(fmaxf(x, 0.f), 1.f);   // v_med3_f32
        y = fminf(fmaxf(y, 0.f), 1.f);
        st.h[rr]      = (_Float16)x;
        st.h[8 + rr]  = (_Float16)y;
        st.h[16 + rr] = (_Float16)fmaf(x, x, y * y);
        st.h[24 + rr] = (_Float16)(x * y);
    }
    const int slot = g ^ ((c >> 1) & 3);
#pragma unroll
    for (int ch = 0; ch < 4; ++ch)
        *reinterpret_cast<f16x8*>(&sm->ch[ch][c][slot * 8]) = st.v8[ch];
}

__global__ __launch_bounds__(NT, 8)
void ssim_mfma(const float* __restrict__ den, const float* __restrict__ cln,
               double* __restrict__ slots) {
    __shared__ SMem sm;

    const int t    = threadIdx.x;
    const int lane = t & 63;
    const int w    = t >> 6;
    const int fj   = lane & 15;   // MFMA i/j index
    const int fg   = lane >> 4;   // MFMA k-group

    // XCD-chunked swizzle: consecutive vids (sharing halo rows) on one XCD
    const int bid = blockIdx.x;
    int vid = bid;
    if ((gridDim.x & 7) == 0) {
        const int chunk = gridDim.x >> 3;
        vid = (bid & 7) * chunk + (bid >> 3);
    }
    const int rs    = vid & 31;
    const int cs    = (vid >> 5) & 7;
    const int plane = vid >> 8;
    const int c0 = cs * OUT_C;
    const int y0 = rs * OUT_R;
    const size_t pbase = (size_t)plane * (IMG * IMG);

    const f16x8 wf = *reinterpret_cast<const f16x8*>(WTAB.v[fg][fj]);

    // ---------------- Phase 1: prep 4 channels in f16 into LDS -------------
    prep_task(t, c0, y0, pbase, den, cln, &sm);
    if (t < 4 * CPAD - NT)                          // 64 leftover tasks
        prep_task(NT + t, c0, y0, pbase, den, cln, &sm);
    __syncthreads();

    // ---------------- Phase 2: vertical conv via MFMA ----------------------
    // D = Wv(16x32) * chbuf(32 x 16cols); 5 tiles * 4 ch = 20 tasks, 5/wave
    const f32x4 zero4 = {0.f, 0.f, 0.f, 0.f};
    f32x4 acc[NVTILE];
#pragma unroll
    for (int n = 0; n < NVTILE; ++n) {
        const int tau  = NVTILE * w + n;
        const int tile = tau >> 2;
        const int ch   = tau & 3;
        const int colp = tile * 16 + fj;
        const f16x8 bf = *reinterpret_cast<const f16x8*>(
            &sm.ch[ch][colp][(fg ^ ((colp >> 1) & 3)) * 8]);
        acc[n] = __builtin_amdgcn_mfma_f32_16x16x32_f16(wf, bf, zero4, 0, 0, 0);
    }
    __syncthreads();   // all chbuf reads done -> safe to alias vb over it
#pragma unroll
    for (int n = 0; n < NVTILE; ++n) {
        const int tau  = NVTILE * w + n;
        const int tile = tau >> 2;
        const int ch   = tau & 3;
#pragma unroll
        for (int b = 0; b < 4; ++b)
            sm.s.vb[ch][4 * fg + b][tile * 16 + fj] = (_Float16)acc[n][b];
    }
    __syncthreads();

    // ---------------- Phase 3: horizontal conv via MFMA + SSIM -------------
    // D = vbuf(16rows x K=32cols) * Wh(32x16); 4 out-tiles, 1 per wave (m=w)
    float sacc = 0.f;
    {
        const int m = w;
        f32x4 d[4];
#pragma unroll
        for (int ch = 0; ch < 4; ++ch) {
            const f16x8 af = *reinterpret_cast<const f16x8*>(
                &sm.s.vb[ch][fj][m * 16 + 8 * fg]);
            d[ch] = __builtin_amdgcn_mfma_f32_16x16x32_f16(af, wf, zero4, 0, 0, 0);
        }
#pragma unroll
        for (int b = 0; b < 4; ++b) {
            const float C1 = 1e-4f, C2 = 9e-4f;
            const float mu1 = d[0][b], mu2 = d[1][b];
            const float qb  = d[2][b], pb  = d[3][b];
            const float mu1s = mu1 * mu1, mu2s = mu2 * mu2, mu12 = mu1 * mu2;
            const float ssum = qb - mu1s - mu2s;    // sigma1_sq + sigma2_sq
            const float s12  = pb - mu12;
            const float num  = fmaf(2.f, mu12, C1) * fmaf(2.f, s12, C2);
            const float dnm  = (mu1s + mu2s + C1) * (ssum + C2);
            sacc = fmaf(num, __builtin_amdgcn_rcpf(dnm), sacc);
        }
    }

    // ---------------- block reduction, one f64 atomic per block ------------
#pragma unroll
    for (int off = 32; off > 0; off >>= 1)
        sacc += __shfl_down(sacc, off, 64);
    if (lane == 0) sm.s.red[w] = sacc;
    __syncthreads();
    if (t == 0) {
        const float s = sm.s.red[0] + sm.s.red[1] + sm.s.red[2] + sm.s.red[3];
        atomicAdd(&slots[(size_t)(bid & (NSLOTS - 1)) * 8], (double)s);
    }
}

__global__ void ssim_finalize(const double* __restrict__ slots,
                              float* __restrict__ out, double inv_n) {
    double s = 0.0;
    for (int i = 0; i < NSLOTS; ++i) s += slots[i * 8];
    out[0] = 1.0f - (float)(s * inv_n);
}

extern "C" void kernel_launch(void* const* d_in, const int* in_sizes, int n_in,
                              void* d_out, int out_size, void* d_ws,
                              size_t ws_size, hipStream_t stream) {
    const float* den = (const float*)d_in[0];
    const float* cln = (const float*)d_in[1];
    float* out = (float*)d_out;
    double* slots = (double*)d_ws;

    hipMemsetAsync(d_ws, 0, NSLOTS * 64, stream);

    const int n = in_sizes[0];                  // 32*3*512*512 elements
    const int planes = n / (IMG * IMG);         // 96
    dim3 grid(planes * (IMG / OUT_R) * (IMG / OUT_C));   // 96*32*8 = 24576
    ssim_mfma<<<grid, NT, 0, stream>>>(den, cln, slots);
    ssim_finalize<<<1, 1, 0, stream>>>(slots, out, 1.0 / (double)n);
}